// Round 1
// baseline (1015.474 us; speedup 1.0000x reference)
//
#include <hip/hip_runtime.h>

#define B_ 2
#define H_ 16
#define S_ 2048
#define D_ 64

typedef short v8s __attribute__((ext_vector_type(8)));   // 8 bf16 (bit patterns) = 4 VGPRs
typedef float v4f __attribute__((ext_vector_type(4)));
typedef unsigned short u16;
typedef unsigned int   u32;
typedef unsigned long long u64;

// pack two fp32 -> two bf16 (round-half-up: +0x8000 then take high 16 via v_perm)
__device__ __forceinline__ u32 pk2(float a, float b) {
    u32 ua = __float_as_uint(a) + 0x8000u;
    u32 ub = __float_as_uint(b) + 0x8000u;
    return __builtin_amdgcn_perm(ub, ua, 0x07060302u);  // lo16=hi(ua), hi16=hi(ub)
}

// load 8 consecutive fp32, scale, convert to bf16x8 fragment
__device__ __forceinline__ v8s cvt8(const float* __restrict__ p, float s) {
    float4 x = ((const float4*)p)[0];
    float4 y = ((const float4*)p)[1];
    union { u32 u[4]; v8s v; } r;
    r.u[0] = pk2(x.x * s, x.y * s);
    r.u[1] = pk2(x.z * s, x.w * s);
    r.u[2] = pk2(y.x * s, y.y * s);
    r.u[3] = pk2(y.z * s, y.w * s);
    return r.v;
}

// ---------------- prep kernels (fast path, workspace-backed) ----------------

// fp32 -> bf16, 8 elems/thread (K matrix)
__global__ void cvt_bf16_k(const float* __restrict__ src, u16* __restrict__ dst) {
    size_t i = (size_t)blockIdx.x * blockDim.x + threadIdx.x;
    const float* p = src + i * 8;
    float4 a = ((const float4*)p)[0], b = ((const float4*)p)[1];
    uint4 o;
    o.x = pk2(a.x, a.y); o.y = pk2(a.z, a.w);
    o.z = pk2(b.x, b.y); o.w = pk2(b.z, b.w);
    ((uint4*)dst)[i] = o;
}

// V[b,h,s,d] fp32 -> Vt[b,h,d,s] bf16 (64x64 tiles through LDS)
__global__ void vtrans_k(const float* __restrict__ V, u16* __restrict__ Vt) {
    __shared__ u16 t[64][66];                       // +2 pad: odd dword stride
    const int bh = blockIdx.y, s0 = blockIdx.x * 64;
    const int tid = threadIdx.x;
    {
        const int r = tid >> 2, c0 = (tid & 3) * 16;
        const float* p = V + ((size_t)bh * S_ + s0 + r) * D_ + c0;
        float4 f0 = ((const float4*)p)[0], f1 = ((const float4*)p)[1];
        float4 f2 = ((const float4*)p)[2], f3 = ((const float4*)p)[3];
        u32* tw = (u32*)&t[r][c0];
        tw[0] = pk2(f0.x, f0.y); tw[1] = pk2(f0.z, f0.w);
        tw[2] = pk2(f1.x, f1.y); tw[3] = pk2(f1.z, f1.w);
        tw[4] = pk2(f2.x, f2.y); tw[5] = pk2(f2.z, f2.w);
        tw[6] = pk2(f3.x, f3.y); tw[7] = pk2(f3.z, f3.w);
    }
    __syncthreads();
    {
        const int d = tid >> 2, sc = (tid & 3) * 16;
        u32 o[8];
        #pragma unroll
        for (int u = 0; u < 8; ++u)
            o[u] = (u32)t[sc + 2 * u][d] | ((u32)t[sc + 2 * u + 1][d] << 16);
        u16* q = Vt + ((size_t)bh * D_ + d) * S_ + s0 + sc;
        ((uint4*)q)[0] = make_uint4(o[0], o[1], o[2], o[3]);
        ((uint4*)q)[1] = make_uint4(o[4], o[5], o[6], o[7]);
    }
}

// mask int32 -> bitmask (1 bit/elem), linear order == flat index; ballot packs a wave
__global__ void mbits_k(const int* __restrict__ mask, u64* __restrict__ mb) {
    size_t i = (size_t)blockIdx.x * blockDim.x + threadIdx.x;
    u64 bal = __ballot(mask[i] != 0);
    if ((threadIdx.x & 63) == 0) mb[i >> 6] = bal;
}

// ---------------- main attention kernel ----------------
// Block: 256 thr = 4 waves; wave w owns q-rows [qb*64 + w*16, +16).
// Pass A: rowsum of masked exp(QK^T/8). Pass B: recompute, write P, O += P*V.
template <bool PREP>
__global__ __launch_bounds__(256, 4)
void attn_main(const float* __restrict__ Q, const float* __restrict__ K,
               const float* __restrict__ V, const int* __restrict__ mask,
               const u16* __restrict__ Kb, const u16* __restrict__ Vt,
               const u32* __restrict__ mbits,
               float* __restrict__ out, float* __restrict__ P)
{
    // per-wave private LDS scratch: 16 rows x 80 B (stride 80 kills write conflicts)
    __shared__ u16 ldsbuf[4][640];
    const int tid = threadIdx.x;
    const int w = tid >> 6, lane = tid & 63;
    const int n = lane & 15, g = lane >> 4;
    const int qb = blockIdx.x, h = blockIdx.y, b = blockIdx.z;
    const int bh = b * H_ + h;
    const int q0 = qb * 64 + w * 16;

    // Q A-fragments, pre-scaled by 1/sqrt(64)=0.125 (exact in bf16)
    const float* qrow = Q + ((size_t)bh * S_ + q0 + n) * D_;
    const v8s aq0 = cvt8(qrow + g * 8, 0.125f);
    const v8s aq1 = cvt8(qrow + 32 + g * 8, 0.125f);

    const u32* mbase = nullptr;
    const int* mrow = nullptr;
    const u16* kbbase = nullptr;
    const float* kfbase = nullptr;
    const u16* vbase = nullptr;
    if constexpr (PREP) {
        mbase  = mbits + ((size_t)b * S_ + q0 + g * 4) * (S_ / 32);
        kbbase = Kb + ((size_t)bh * S_ + n) * D_ + g * 8;
        vbase  = Vt + ((size_t)bh * D_ + n) * S_ + g * 4;
    } else {
        mrow   = mask + ((size_t)b * S_ + q0 + g * 4) * S_ + n;
        kfbase = K + ((size_t)bh * S_ + n) * D_ + g * 8;
    }

    // B-frag of K for tile [key0, key0+16), d-half dh: B[k=d][n=key]
    auto loadK = [&](int key0, int dh) -> v8s {
        if constexpr (PREP) {
            return *(const v8s*)(kbbase + (size_t)key0 * D_ + dh * 32);
        } else {
            return cvt8(kfbase + (size_t)key0 * D_ + dh * 32, 1.0f);
        }
    };
    // 32 mask bits for row (q0+g*4+i), keys [k0,k0+32): bit n -> k0+n, bit n+16 -> k0+16+n
    auto loadM = [&](int i, int k0) -> u32 {
        if constexpr (PREP) {
            return mbase[i * (S_ / 32) + (k0 >> 5)];
        } else {
            u32 r = 0;
            if (mrow[(size_t)i * S_ + k0]) r |= 1u << n;
            if (mrow[(size_t)i * S_ + k0 + 16]) r |= 1u << (n + 16);
            return r;
        }
    };
    // B-frag of V in kappa-interleaved order: elem j <-> key k0 + 16*(j&1) + 4g + (j>>1)
    auto loadV = [&](int k0, int dt) -> v8s {
        union { u32 u[4]; v8s v; } r;
        if constexpr (PREP) {
            const u16* vp = vbase + (size_t)dt * 16 * S_ + k0;
            uint2 ra = *(const uint2*)vp;         // keys k0+4g+0..3
            uint2 rb = *(const uint2*)(vp + 16);  // keys k0+16+4g+0..3
            r.u[0] = __builtin_amdgcn_perm(rb.x, ra.x, 0x05040100u);
            r.u[1] = __builtin_amdgcn_perm(rb.x, ra.x, 0x07060302u);
            r.u[2] = __builtin_amdgcn_perm(rb.y, ra.y, 0x05040100u);
            r.u[3] = __builtin_amdgcn_perm(rb.y, ra.y, 0x07060302u);
        } else {
            const float* vp = V + ((size_t)bh * S_ + k0 + g * 4) * D_ + dt * 16 + n;
            #pragma unroll
            for (int p2 = 0; p2 < 4; ++p2) {
                float fa = vp[(size_t)p2 * D_];
                float fb = vp[(size_t)(16 + p2) * D_];
                r.u[p2] = pk2(fa, fb);
            }
        }
        return r.v;
    };

    // ---- Pass A: row sums of masked exp ----
    v4f sum = {0.f, 0.f, 0.f, 0.f};
    for (int k0 = 0; k0 < S_; k0 += 32) {
        v4f a0 = {0.f, 0.f, 0.f, 0.f}, a1 = {0.f, 0.f, 0.f, 0.f};
        a0 = __builtin_amdgcn_mfma_f32_16x16x32_bf16(aq0, loadK(k0, 0), a0, 0, 0, 0);
        a0 = __builtin_amdgcn_mfma_f32_16x16x32_bf16(aq1, loadK(k0, 1), a0, 0, 0, 0);
        a1 = __builtin_amdgcn_mfma_f32_16x16x32_bf16(aq0, loadK(k0 + 16, 0), a1, 0, 0, 0);
        a1 = __builtin_amdgcn_mfma_f32_16x16x32_bf16(aq1, loadK(k0 + 16, 1), a1, 0, 0, 0);
        #pragma unroll
        for (int i = 0; i < 4; ++i) {
            u32 mw = loadM(i, k0);
            float e0 = ((mw >> n) & 1) ? __expf(a0[i]) : 0.f;
            float e1 = ((mw >> (n + 16)) & 1) ? __expf(a1[i]) : 0.f;
            sum[i] += e0 + e1;
        }
    }
    // reduce over the 16 lanes sharing each g-group; then invert
    #pragma unroll
    for (int i = 0; i < 4; ++i) {
        float s = sum[i];
        s += __shfl_xor(s, 1, 64);
        s += __shfl_xor(s, 2, 64);
        s += __shfl_xor(s, 4, 64);
        s += __shfl_xor(s, 8, 64);
        sum[i] = 1.0f / s;   // sum now holds inv
    }

    // ---- Pass B: write P, accumulate O = P*V ----
    char* ldsw = (char*)&ldsbuf[w][0];
    float* pbase = P + ((size_t)bh * S_ + q0 + g * 4) * S_ + n;
    v4f o0 = {0.f, 0.f, 0.f, 0.f}, o1 = o0, o2 = o0, o3 = o0;

    for (int k0 = 0; k0 < S_; k0 += 32) {
        v4f a0 = {0.f, 0.f, 0.f, 0.f}, a1 = {0.f, 0.f, 0.f, 0.f};
        a0 = __builtin_amdgcn_mfma_f32_16x16x32_bf16(aq0, loadK(k0, 0), a0, 0, 0, 0);
        a0 = __builtin_amdgcn_mfma_f32_16x16x32_bf16(aq1, loadK(k0, 1), a0, 0, 0, 0);
        a1 = __builtin_amdgcn_mfma_f32_16x16x32_bf16(aq0, loadK(k0 + 16, 0), a1, 0, 0, 0);
        a1 = __builtin_amdgcn_mfma_f32_16x16x32_bf16(aq1, loadK(k0 + 16, 1), a1, 0, 0, 0);
        #pragma unroll
        for (int i = 0; i < 4; ++i) {
            u32 mw = loadM(i, k0);
            float p0 = ((mw >> n) & 1) ? __expf(a0[i]) * sum[i] : 0.f;
            float p1 = ((mw >> (n + 16)) & 1) ? __expf(a1[i]) * sum[i] : 0.f;
            pbase[(size_t)i * S_ + k0] = p0;
            pbase[(size_t)i * S_ + k0 + 16] = p1;
            // LDS: row r=g*4+i stride 80B; kappa pair (2n,2n+1) -> one b32 write
            *(u32*)(ldsw + (g * 4 + i) * 80 + (n >> 2) * 16 + (n & 3) * 4) = pk2(p0, p1);
        }
        // A-frag of P: lane row = lane&15 (=n), kappa block = g -> 16 contiguous bytes
        v8s ap = *(const v8s*)(ldsw + n * 80 + g * 16);
        o0 = __builtin_amdgcn_mfma_f32_16x16x32_bf16(ap, loadV(k0, 0), o0, 0, 0, 0);
        o1 = __builtin_amdgcn_mfma_f32_16x16x32_bf16(ap, loadV(k0, 1), o1, 0, 0, 0);
        o2 = __builtin_amdgcn_mfma_f32_16x16x32_bf16(ap, loadV(k0, 2), o2, 0, 0, 0);
        o3 = __builtin_amdgcn_mfma_f32_16x16x32_bf16(ap, loadV(k0, 3), o3, 0, 0, 0);
    }

    float* obase = out + ((size_t)bh * S_ + q0 + g * 4) * D_ + n;
    #pragma unroll
    for (int i = 0; i < 4; ++i) {
        obase[(size_t)i * D_]      = o0[i];
        obase[(size_t)i * D_ + 16] = o1[i];
        obase[(size_t)i * D_ + 32] = o2[i];
        obase[(size_t)i * D_ + 48] = o3[i];
    }
}

extern "C" void kernel_launch(void* const* d_in, const int* in_sizes, int n_in,
                              void* d_out, int out_size, void* d_ws, size_t ws_size,
                              hipStream_t stream)
{
    (void)in_sizes; (void)n_in; (void)out_size;
    const float* Q = (const float*)d_in[0];
    const float* K = (const float*)d_in[1];
    const float* V = (const float*)d_in[2];
    const int* mask = (const int*)d_in[3];
    float* out = (float*)d_out;
    float* P = out + (size_t)B_ * H_ * S_ * D_;   // p_attn follows out in d_out

    const size_t kb_b = (size_t)B_ * H_ * S_ * D_ * 2;  // 8 MB  bf16 K
    const size_t vt_b = kb_b;                            // 8 MB  bf16 V^T
    const size_t mb_b = (size_t)B_ * S_ * S_ / 8;        // 1 MB  mask bits
    dim3 mgrid(S_ / 64, H_, B_);

    if (ws_size >= kb_b + vt_b + mb_b) {
        u16* Kb = (u16*)d_ws;
        u16* Vt = (u16*)((char*)d_ws + kb_b);
        u64* mb = (u64*)((char*)d_ws + kb_b + vt_b);
        cvt_bf16_k<<<(B_ * H_ * S_ * D_) / (256 * 8), 256, 0, stream>>>(K, Kb);
        vtrans_k<<<dim3(S_ / 64, B_ * H_), 256, 0, stream>>>(V, Vt);
        mbits_k<<<(B_ * S_ * S_) / 256, 256, 0, stream>>>(mask, mb);
        attn_main<true><<<mgrid, 256, 0, stream>>>(Q, K, V, mask, Kb, Vt, (const u32*)mb, out, P);
    } else {
        attn_main<false><<<mgrid, 256, 0, stream>>>(Q, K, V, mask, nullptr, nullptr, nullptr, out, P);
    }
}